// Round 3
// baseline (182.824 us; speedup 1.0000x reference)
//
#include <hip/hip_runtime.h>
#include <hip/hip_bf16.h>

typedef __hip_bfloat16 bf16;
typedef short bf16x8 __attribute__((ext_vector_type(8)));
typedef float f32x4 __attribute__((ext_vector_type(4)));

#define NGRAPH 16
#define QSCALE 0.17677669529663687f
#define VT_LD 8192  // V^T leading dim: 16 graphs x 512 slots

struct __align__(16) bf8x { bf16 v[8]; };

__device__ __forceinline__ float b2f(bf16 v) { return __bfloat162float(v); }

// load 8 consecutive f32 and convert to a bf16x8 A/B fragment
__device__ __forceinline__ bf16x8 ldcvt8(const float* p) {
  float4 u = *(const float4*)p, v = *(const float4*)(p + 4);
  __align__(16) bf16 tmp[8];
  tmp[0] = __float2bfloat16(u.x); tmp[1] = __float2bfloat16(u.y);
  tmp[2] = __float2bfloat16(u.z); tmp[3] = __float2bfloat16(u.w);
  tmp[4] = __float2bfloat16(v.x); tmp[5] = __float2bfloat16(v.y);
  tmp[6] = __float2bfloat16(v.z); tmp[7] = __float2bfloat16(v.w);
  return *(const bf16x8*)tmp;
}

// ---------------- K1: W transposes + graph offsets + global bias table ----------------
// bias table: T[384][8] f32, T[i][h] = sum_r W[r,h] cos((i/8)*|f_r|)  (identical for all
// attn blocks -> build once here instead of per-block in k_attn)
__global__ __launch_bounds__(256) void k_pre(const float* __restrict__ Wqkv,
                                             const float* __restrict__ Wout,
                                             const int* __restrict__ batch,
                                             const float* __restrict__ freqs,
                                             const float* __restrict__ Wrope,
                                             bf16* __restrict__ Wqkv_t,
                                             bf16* __restrict__ Wout_t,
                                             float* __restrict__ Tblg,
                                             int* __restrict__ offs, int N) {
  __shared__ float ld[64][65];
  int bid = blockIdx.x, t = threadIdx.x;
  int c = t & 63, r0 = t >> 6;
  if (bid < 48) {  // Wqkv [256][768] -> Wqkv_t [768][256]
    int k0 = (bid & 3) * 64, n0 = (bid >> 2) * 64;
    #pragma unroll
    for (int r = r0; r < 64; r += 4) ld[r][c] = Wqkv[(size_t)(k0 + r) * 768 + n0 + c];
    __syncthreads();
    #pragma unroll
    for (int r = r0; r < 64; r += 4)
      Wqkv_t[(size_t)(n0 + r) * 256 + k0 + c] = __float2bfloat16(ld[c][r]);
  } else if (bid < 64) {  // Wout [256][256] -> Wout_t [256][256]
    int b2 = bid - 48;
    int k0 = (b2 & 3) * 64, n0 = (b2 >> 2) * 64;
    #pragma unroll
    for (int r = r0; r < 64; r += 4) ld[r][c] = Wout[(size_t)(k0 + r) * 256 + n0 + c];
    __syncthreads();
    #pragma unroll
    for (int r = r0; r < 64; r += 4)
      Wout_t[(size_t)(n0 + r) * 256 + k0 + c] = __float2bfloat16(ld[c][r]);
  } else if (bid == 64) {  // offsets from sorted batch ids
    for (int i = t; i < N; i += 256) {
      if (i == 0) { offs[0] = 0; offs[NGRAPH] = N; }
      else if (batch[i] != batch[i - 1]) offs[batch[i]] = i;
    }
  } else {  // bid 65,66: bias table rows
    int i = (bid - 65) * 256 + t;
    if (i < 384) {
      float d = i * 0.125f;
      float a[8];
      #pragma unroll
      for (int h = 0; h < 8; ++h) a[h] = 0.f;
      #pragma unroll
      for (int r = 0; r < 16; ++r) {
        float cv = __cosf(d * fabsf(freqs[r]));
        #pragma unroll
        for (int h = 0; h < 8; ++h) a[h] += cv * Wrope[r * 8 + h];
      }
      #pragma unroll
      for (int h = 0; h < 8; ++h) Tblg[i * 8 + h] = a[h];
    }
  }
}

// ---------------- K2: QKV GEMM, A-fragment reused across Q/K/V groups + V^T ----------------
// grid (M/32, 4): block does 32 rows x (three 64-col groups). 4 waves = 2 row-halves x
// 2 col-halves -> 768 blocks (12 waves/CU) for latency hiding.
__global__ __launch_bounds__(256) void k_gemm(const float* __restrict__ x,
                                              const bf16* __restrict__ Wqkv_t,
                                              const int* __restrict__ batch,
                                              const int* __restrict__ offs,
                                              bf16* __restrict__ QKVb,
                                              bf16* __restrict__ VT, int N) {
  __shared__ float tr[64][33];
  __shared__ int rowcol[32];
  int t = threadIdx.x;
  int w = t >> 6, l = t & 63, fr = l & 15, fq = l >> 4;
  int rh = w & 1, ch = w >> 1;
  int m0 = blockIdx.x * 32, n0 = blockIdx.y * 64;
  if (t < 32) {
    int m = m0 + t; if (m > N - 1) m = N - 1;
    int b = batch[m];
    rowcol[t] = b * 512 + (m - offs[b]);
  }
  int arow = m0 + rh * 16 + fr; if (arow > N - 1) arow = N - 1;
  bf16x8 af[8];
  #pragma unroll
  for (int kt = 0; kt < 8; ++kt)
    af[kt] = ldcvt8(x + (size_t)arow * 256 + kt * 32 + fq * 8);
  #pragma unroll
  for (int p = 0; p < 3; ++p) {
    f32x4 acc[2];
    #pragma unroll
    for (int nt = 0; nt < 2; ++nt) {
      acc[nt] = (f32x4){0.f, 0.f, 0.f, 0.f};
      int brow = p * 256 + n0 + ch * 32 + nt * 16 + fr;
      #pragma unroll
      for (int kt = 0; kt < 8; ++kt) {
        bf16x8 bf_ = *(const bf16x8*)(Wqkv_t + (size_t)brow * 256 + kt * 32 + fq * 8);
        acc[nt] = __builtin_amdgcn_mfma_f32_16x16x32_bf16(af[kt], bf_, acc[nt], 0, 0, 0);
      }
    }
    float sc = (p == 0) ? QSCALE : 1.f;
    #pragma unroll
    for (int nt = 0; nt < 2; ++nt) {
      int col = p * 256 + n0 + ch * 32 + nt * 16 + fr;
      #pragma unroll
      for (int rr = 0; rr < 4; ++rr) {
        int m = m0 + rh * 16 + fq * 4 + rr;
        if (m < N) QKVb[(size_t)m * 768 + col] = __float2bfloat16(acc[nt][rr] * sc);
      }
    }
    if (p == 2) {  // V^T side output
      #pragma unroll
      for (int nt = 0; nt < 2; ++nt)
        #pragma unroll
        for (int rr = 0; rr < 4; ++rr)
          tr[ch * 32 + nt * 16 + fr][rh * 16 + fq * 4 + rr] = acc[nt][rr];
      __syncthreads();
      int c = t >> 2, rr0 = (t & 3) * 8;
      int dg = n0 + c;  // head*32 + d
      #pragma unroll
      for (int i = 0; i < 8; ++i) {
        int r = rr0 + i;
        VT[(size_t)dg * VT_LD + rowcol[r]] = __float2bfloat16(tr[c][r]);
      }
    }
  }
}

// ---------------- K3: fused MFMA flash attention; bias via precomputed LDS table ----------------
// block = (q-tile 16, graph, j-chunk of JC). 4 waves, wave = heads {w, w+4}.
__global__ __launch_bounds__(256) void k_attn(const float* __restrict__ pos,
                                              const float* __restrict__ Tblg,
                                              const bf16* __restrict__ QKVb,
                                              const bf16* __restrict__ VT,
                                              const int* __restrict__ offs,
                                              float* __restrict__ Op,
                                              float* __restrict__ lp, int N, int JC) {
  __shared__ __align__(16) float Tgf[384][8];      // bias table [d_idx][head] (f32)
  __shared__ __align__(16) bf16 Sbf[2][8][64][8];  // bias tiles in MFMA C-frag order
  __shared__ __align__(16) bf16 Pt[4][16][40];     // per-wave P C->A transform
  int b = blockIdx.y, jc = blockIdx.z;
  int off = offs[b], n = offs[b + 1] - off;
  int q0 = blockIdx.x * 16;
  if (q0 >= n) return;
  int t = threadIdx.x, w = t >> 6, l = t & 63, fr = l & 15, fq = l >> 4;

  // ---- copy bias table global -> LDS (768 float4) ----
  {
    float4* dst = (float4*)&Tgf[0][0];
    const float4* src = (const float4*)Tblg;
    #pragma unroll
    for (int i = t; i < 768; i += 256) dst[i] = src[i];
  }

  int h0 = w, h1 = w + 4;
  const bf16* Kb0 = QKVb + (size_t)off * 768 + 256 + h0 * 32 + fq * 8;
  const bf16* Kb1 = QKVb + (size_t)off * 768 + 256 + h1 * 32 + fq * 8;
  const bf16* Vb0 = VT + (size_t)(h0 * 32 + fr) * VT_LD + b * 512 + fq * 8;
  const bf16* Vb1 = VT + (size_t)(h1 * 32 + fr) * VT_LD + b * 512 + fq * 8;
  int qrow = q0 + fr; bool qv = qrow < n;
  size_t qoff = (size_t)(qv ? off + qrow : off) * 768 + fq * 8;
  bf16x8 aq[2];
  aq[0] = *(const bf16x8*)(QKVb + qoff + h0 * 32);
  aq[1] = *(const bf16x8*)(QKVb + qoff + h1 * 32);
  if (!qv) { aq[0] = (bf16x8){0,0,0,0,0,0,0,0}; aq[1] = aq[0]; }

  // bias producer role: thread owns pairs (q=bq, j=bj) and (q=bq+8, j=bj)
  int bq = t >> 5, bj = t & 31;
  float qpx[2], qpy[2], qpz[2]; bool bqv[2];
  #pragma unroll
  for (int e = 0; e < 2; ++e) {
    int qq = q0 + bq + 8 * e; bqv[e] = qq < n;
    int a = (bqv[e] ? off + qq : off) * 3;
    qpx[e] = pos[a]; qpy[e] = pos[a + 1]; qpz[e] = pos[a + 2];
  }

  f32x4 Oa[2][2];
  Oa[0][0] = (f32x4){0.f,0.f,0.f,0.f}; Oa[0][1] = Oa[0][0];
  Oa[1][0] = Oa[0][0];                 Oa[1][1] = Oa[0][0];
  float lacc[2][4] = {{0.f,0.f,0.f,0.f},{0.f,0.f,0.f,0.f}};
  int jtiles = (n + 31) >> 5;
  int jt0 = (jtiles * jc) / JC, jt1 = (jtiles * (jc + 1)) / JC;

  auto produce = [&](int JT, int BUF) {
    int jg = JT * 32 + bj; bool vj = jg < n;
    int a = (vj ? off + jg : off) * 3;
    float jx = pos[a], jy = pos[a + 1], jz = pos[a + 2];
    #pragma unroll
    for (int e = 0; e < 2; ++e) {
      int q = bq + 8 * e;
      int L = (q >> 2) * 16 + (bj & 15);
      int k = (bj >> 4) * 4 + (q & 3);
      if (vj && bqv[e]) {
        float dx = qpx[e] - jx, dy = qpy[e] - jy, dz = qpz[e] - jz;
        float d = sqrtf(dx * dx + dy * dy + dz * dz);
        float fi = d * 8.0f;
        int i = (int)fi; if (i > 382) i = 382;
        float fr2 = fi - (float)i;
        const float* tp = &Tgf[i][0];
        float4 a0 = *(const float4*)tp,       a1 = *(const float4*)(tp + 4);
        float4 c0 = *(const float4*)(tp + 8), c1 = *(const float4*)(tp + 12);
        Sbf[BUF][0][L][k] = __float2bfloat16(a0.x + fr2 * (c0.x - a0.x));
        Sbf[BUF][1][L][k] = __float2bfloat16(a0.y + fr2 * (c0.y - a0.y));
        Sbf[BUF][2][L][k] = __float2bfloat16(a0.z + fr2 * (c0.z - a0.z));
        Sbf[BUF][3][L][k] = __float2bfloat16(a0.w + fr2 * (c0.w - a0.w));
        Sbf[BUF][4][L][k] = __float2bfloat16(a1.x + fr2 * (c1.x - a1.x));
        Sbf[BUF][5][L][k] = __float2bfloat16(a1.y + fr2 * (c1.y - a1.y));
        Sbf[BUF][6][L][k] = __float2bfloat16(a1.z + fr2 * (c1.z - a1.z));
        Sbf[BUF][7][L][k] = __float2bfloat16(a1.w + fr2 * (c1.w - a1.w));
      } else {
        bf16 s = __float2bfloat16(vj ? 0.f : -1e30f);
        #pragma unroll
        for (int h = 0; h < 8; ++h) Sbf[BUF][h][L][k] = s;
      }
    }
  };

  bf16x8 ck[2][2], cv[2][2];
  auto loadt = [&](int JT) {
    int k0 = JT * 32 + fr, k1 = k0 + 16;
    size_t r0 = (size_t)((k0 < n) ? k0 : 0) * 768;
    size_t r1 = (size_t)((k1 < n) ? k1 : 0) * 768;
    ck[0][0] = *(const bf16x8*)(Kb0 + r0); ck[0][1] = *(const bf16x8*)(Kb0 + r1);
    ck[1][0] = *(const bf16x8*)(Kb1 + r0); ck[1][1] = *(const bf16x8*)(Kb1 + r1);
    cv[0][0] = *(const bf16x8*)(Vb0 + JT * 32);
    cv[0][1] = *(const bf16x8*)(Vb0 + (size_t)16 * VT_LD + JT * 32);
    cv[1][0] = *(const bf16x8*)(Vb1 + JT * 32);
    cv[1][1] = *(const bf16x8*)(Vb1 + (size_t)16 * VT_LD + JT * 32);
  };

  __syncthreads();          // table ready
  produce(jt0, 0);
  __syncthreads();
  for (int jt = jt0; jt < jt1; ++jt) {
    int par = (jt - jt0) & 1;
    loadt(jt);                               // global loads: latency hidden by produce()
    if (jt + 1 < jt1) produce(jt + 1, par ^ 1);
    #pragma unroll
    for (int hh = 0; hh < 2; ++hh) {
      int h = w + 4 * hh;
      f32x4 z = {0.f, 0.f, 0.f, 0.f};
      f32x4 S0 = __builtin_amdgcn_mfma_f32_16x16x32_bf16(aq[hh], ck[hh][0], z, 0, 0, 0);
      f32x4 S1 = __builtin_amdgcn_mfma_f32_16x16x32_bf16(aq[hh], ck[hh][1], z, 0, 0, 0);
      bf8x bb = *(const bf8x*)&Sbf[par][h][l][0];
      #pragma unroll
      for (int k = 0; k < 8; ++k) {
        int jti = k >> 2, rr = k & 3;
        float s = (jti ? S1[rr] : S0[rr]) + b2f(bb.v[k]);
        float p = __expf(s);
        lacc[hh][rr] += p;
        Pt[w][fq * 4 + rr][jti * 16 + fr] = __float2bfloat16(p);
      }
      bf16x8 ap = *(const bf16x8*)&Pt[w][fr][fq * 8];
      Oa[hh][0] = __builtin_amdgcn_mfma_f32_16x16x32_bf16(ap, cv[hh][0], Oa[hh][0], 0, 0, 0);
      Oa[hh][1] = __builtin_amdgcn_mfma_f32_16x16x32_bf16(ap, cv[hh][1], Oa[hh][1], 0, 0, 0);
    }
    __syncthreads();
  }
  #pragma unroll
  for (int hh = 0; hh < 2; ++hh)
    #pragma unroll
    for (int rr = 0; rr < 4; ++rr) {
      #pragma unroll
      for (int m2 = 1; m2 <= 8; m2 <<= 1) lacc[hh][rr] += __shfl_xor(lacc[hh][rr], m2);
    }
  float* Opc = Op + (size_t)jc * N * 256;
  float* lpc = lp + (size_t)jc * N * 8;
  #pragma unroll
  for (int hh = 0; hh < 2; ++hh) {
    int h = w + 4 * hh;
    #pragma unroll
    for (int rr = 0; rr < 4; ++rr) {
      int row = q0 + fq * 4 + rr;
      if (row < n) {
        #pragma unroll
        for (int dh = 0; dh < 2; ++dh)
          Opc[(size_t)(off + row) * 256 + h * 32 + dh * 16 + fr] = Oa[hh][dh][rr];
        if (fr == 0) lpc[(size_t)(off + row) * 8 + h] = lacc[hh][rr];
      }
    }
  }
}

// ---------------- K4: combine JC j-partials + out-proj GEMM + residual + LN ----------------
__global__ __launch_bounds__(256) void k_out_ln(const float* __restrict__ Op,
                                                const float* __restrict__ lp,
                                                const bf16* __restrict__ Bt,
                                                const float* __restrict__ x,
                                                const float* __restrict__ gamma,
                                                const float* __restrict__ beta,
                                                float* __restrict__ out, int M, int JC) {
  __shared__ float ps[4][16], pss[4][16];
  int t = threadIdx.x, w = t >> 6, l = t & 63, fr = l & 15, fq = l >> 4;
  int m0 = blockIdx.x * 16;
  int arow = m0 + fr; if (arow > M - 1) arow = M - 1;
  float linv[8];
  {
    float ls[8] = {0.f,0.f,0.f,0.f,0.f,0.f,0.f,0.f};
    for (int c = 0; c < JC; ++c) {
      const float* p = lp + ((size_t)c * M + arow) * 8;
      float4 a0 = *(const float4*)p, a1 = *(const float4*)(p + 4);
      ls[0] += a0.x; ls[1] += a0.y; ls[2] += a0.z; ls[3] += a0.w;
      ls[4] += a1.x; ls[5] += a1.y; ls[6] += a1.z; ls[7] += a1.w;
    }
    #pragma unroll
    for (int h = 0; h < 8; ++h) linv[h] = 1.f / ls[h];
  }
  bf16x8 af[8];
  #pragma unroll
  for (int kt = 0; kt < 8; ++kt) {  // head h == kt (32 d per head)
    size_t o = (size_t)arow * 256 + kt * 32 + fq * 8;
    float s0 = 0.f, s1 = 0.f, s2 = 0.f, s3 = 0.f, s4 = 0.f, s5 = 0.f, s6 = 0.f, s7 = 0.f;
    for (int c = 0; c < JC; ++c) {
      const float* p = Op + (size_t)c * M * 256 + o;
      float4 u = *(const float4*)p, v = *(const float4*)(p + 4);
      s0 += u.x; s1 += u.y; s2 += u.z; s3 += u.w;
      s4 += v.x; s5 += v.y; s6 += v.z; s7 += v.w;
    }
    float li = linv[kt];
    __align__(16) bf16 tmp[8];
    tmp[0] = __float2bfloat16(s0 * li); tmp[1] = __float2bfloat16(s1 * li);
    tmp[2] = __float2bfloat16(s2 * li); tmp[3] = __float2bfloat16(s3 * li);
    tmp[4] = __float2bfloat16(s4 * li); tmp[5] = __float2bfloat16(s5 * li);
    tmp[6] = __float2bfloat16(s6 * li); tmp[7] = __float2bfloat16(s7 * li);
    af[kt] = *(const bf16x8*)tmp;
  }
  f32x4 acc[4];
  #pragma unroll
  for (int nt = 0; nt < 4; ++nt) {
    acc[nt] = (f32x4){0.f, 0.f, 0.f, 0.f};
    int brow = w * 64 + nt * 16 + fr;
    #pragma unroll
    for (int kt = 0; kt < 8; ++kt) {
      bf16x8 bf_ = *(const bf16x8*)(Bt + (size_t)brow * 256 + kt * 32 + fq * 8);
      acc[nt] = __builtin_amdgcn_mfma_f32_16x16x32_bf16(af[kt], bf_, acc[nt], 0, 0, 0);
    }
  }
  float y[4][4];
  #pragma unroll
  for (int rr = 0; rr < 4; ++rr) {
    int row = m0 + fq * 4 + rr;
    int rc = (row < M) ? row : (M - 1);
    float s = 0.f, ss = 0.f;
    #pragma unroll
    for (int nt = 0; nt < 4; ++nt) {
      float v = acc[nt][rr] + x[(size_t)rc * 256 + w * 64 + nt * 16 + fr];
      y[rr][nt] = v; s += v; ss += v * v;
    }
    #pragma unroll
    for (int m2 = 1; m2 <= 8; m2 <<= 1) { s += __shfl_xor(s, m2); ss += __shfl_xor(ss, m2); }
    if (fr == 0) { ps[w][fq * 4 + rr] = s; pss[w][fq * 4 + rr] = ss; }
  }
  __syncthreads();
  #pragma unroll
  for (int rr = 0; rr < 4; ++rr) {
    int row = m0 + fq * 4 + rr;
    int ri = fq * 4 + rr;
    float s = ps[0][ri] + ps[1][ri] + ps[2][ri] + ps[3][ri];
    float ss = pss[0][ri] + pss[1][ri] + pss[2][ri] + pss[3][ri];
    float mean = s * (1.f / 256.f);
    float var = ss * (1.f / 256.f) - mean * mean;
    float rstd = rsqrtf(var + 1e-5f);
    if (row < M) {
      #pragma unroll
      for (int nt = 0; nt < 4; ++nt) {
        int col = w * 64 + nt * 16 + fr;
        out[(size_t)row * 256 + col] = gamma[col] * (y[rr][nt] - mean) * rstd + beta[col];
      }
    }
  }
}

extern "C" void kernel_launch(void* const* d_in, const int* in_sizes, int n_in,
                              void* d_out, int out_size, void* d_ws, size_t ws_size,
                              hipStream_t stream) {
  (void)n_in; (void)out_size;
  const float* x     = (const float*)d_in[0];
  const float* pos   = (const float*)d_in[1];
  const int*   batch = (const int*)d_in[2];
  const float* Wqkv  = (const float*)d_in[3];
  const float* Wout  = (const float*)d_in[4];
  const float* freqs = (const float*)d_in[5];
  const float* Wrope = (const float*)d_in[6];
  const float* gamma = (const float*)d_in[7];
  const float* beta  = (const float*)d_in[8];
  float* out = (float*)d_out;

  int N = in_sizes[0] / 256;  // 6137

  // 4-way j-split needs ~40.1 MB of workspace; fall back to 2-way if tight
  int JC = (ws_size >= (size_t)41 * 1024 * 1024) ? 4 : 2;

  char* base = (char*)d_ws;
  int*   offs   = (int*)base;                   // @0 (1 KB)
  bf16*  QKVb   = (bf16*)(base + 1024);         // N*768*2  = 9,426,432
  bf16*  VT     = (bf16*)(base + 9427456);      // 4,194,304
  bf16*  Wqkv_t = (bf16*)(base + 13621760);     // 393,216
  bf16*  Wout_t = (bf16*)(base + 14014976);     // 131,072
  float* Tblg   = (float*)(base + 14146048);    // 12,288
  float* Op     = (float*)(base + 14158336);    // JC x N*256*4
  float* lp     = (float*)(base + 14158336 + (size_t)JC * N * 1024);  // JC x N*8*4

  int MBm = (N + 31) / 32;  // 192
  k_pre<<<67, 256, 0, stream>>>(Wqkv, Wout, batch, freqs, Wrope, Wqkv_t, Wout_t, Tblg, offs, N);
  k_gemm<<<dim3(MBm, 4), 256, 0, stream>>>(x, Wqkv_t, batch, offs, QKVb, VT, N);
  k_attn<<<dim3(32, NGRAPH, JC), 256, 0, stream>>>(pos, Tblg, QKVb, VT, offs, Op, lp, N, JC);
  k_out_ln<<<(N + 15) / 16, 256, 0, stream>>>(Op, lp, Wout_t, x, gamma, beta, out, N, JC);
}

// Round 4
// 180.321 us; speedup vs baseline: 1.0139x; 1.0139x over previous
//
#include <hip/hip_runtime.h>
#include <hip/hip_bf16.h>

typedef __hip_bfloat16 bf16;
typedef short bf16x8 __attribute__((ext_vector_type(8)));
typedef float f32x4 __attribute__((ext_vector_type(4)));

#define NGRAPH 16
#define QSCALE 0.17677669529663687f
#define VT_LD 8192  // V^T leading dim: 16 graphs x 512 slots

// load 8 consecutive f32 and convert to a bf16x8 A/B fragment
__device__ __forceinline__ bf16x8 ldcvt8(const float* p) {
  float4 u = *(const float4*)p, v = *(const float4*)(p + 4);
  __align__(16) bf16 tmp[8];
  tmp[0] = __float2bfloat16(u.x); tmp[1] = __float2bfloat16(u.y);
  tmp[2] = __float2bfloat16(u.z); tmp[3] = __float2bfloat16(u.w);
  tmp[4] = __float2bfloat16(v.x); tmp[5] = __float2bfloat16(v.y);
  tmp[6] = __float2bfloat16(v.z); tmp[7] = __float2bfloat16(v.w);
  return *(const bf16x8*)tmp;
}

// ---------------- K1: W transposes + graph offsets + global bias table ----------------
__global__ __launch_bounds__(256) void k_pre(const float* __restrict__ Wqkv,
                                             const float* __restrict__ Wout,
                                             const int* __restrict__ batch,
                                             const float* __restrict__ freqs,
                                             const float* __restrict__ Wrope,
                                             bf16* __restrict__ Wqkv_t,
                                             bf16* __restrict__ Wout_t,
                                             float* __restrict__ Tblg,
                                             int* __restrict__ offs, int N) {
  __shared__ float ld[64][65];
  int bid = blockIdx.x, t = threadIdx.x;
  int c = t & 63, r0 = t >> 6;
  if (bid < 48) {  // Wqkv [256][768] -> Wqkv_t [768][256]
    int k0 = (bid & 3) * 64, n0 = (bid >> 2) * 64;
    #pragma unroll
    for (int r = r0; r < 64; r += 4) ld[r][c] = Wqkv[(size_t)(k0 + r) * 768 + n0 + c];
    __syncthreads();
    #pragma unroll
    for (int r = r0; r < 64; r += 4)
      Wqkv_t[(size_t)(n0 + r) * 256 + k0 + c] = __float2bfloat16(ld[c][r]);
  } else if (bid < 64) {  // Wout [256][256] -> Wout_t [256][256]
    int b2 = bid - 48;
    int k0 = (b2 & 3) * 64, n0 = (b2 >> 2) * 64;
    #pragma unroll
    for (int r = r0; r < 64; r += 4) ld[r][c] = Wout[(size_t)(k0 + r) * 256 + n0 + c];
    __syncthreads();
    #pragma unroll
    for (int r = r0; r < 64; r += 4)
      Wout_t[(size_t)(n0 + r) * 256 + k0 + c] = __float2bfloat16(ld[c][r]);
  } else if (bid == 64) {  // offsets from sorted batch ids
    for (int i = t; i < N; i += 256) {
      if (i == 0) { offs[0] = 0; offs[NGRAPH] = N; }
      else if (batch[i] != batch[i - 1]) offs[batch[i]] = i;
    }
  } else {  // bid 65,66: bias table rows, T[i][h] = sum_r W[r,h] cos((i/8)|f_r|)
    int i = (bid - 65) * 256 + t;
    if (i < 384) {
      float d = i * 0.125f;
      float a[8];
      #pragma unroll
      for (int h = 0; h < 8; ++h) a[h] = 0.f;
      #pragma unroll
      for (int r = 0; r < 16; ++r) {
        float cv = __cosf(d * fabsf(freqs[r]));
        #pragma unroll
        for (int h = 0; h < 8; ++h) a[h] += cv * Wrope[r * 8 + h];
      }
      #pragma unroll
      for (int h = 0; h < 8; ++h) Tblg[i * 8 + h] = a[h];
    }
  }
}

// ---------------- K2: QKV GEMM, A-fragment reused across Q/K/V groups + V^T ----------------
__global__ __launch_bounds__(256) void k_gemm(const float* __restrict__ x,
                                              const bf16* __restrict__ Wqkv_t,
                                              const int* __restrict__ batch,
                                              const int* __restrict__ offs,
                                              bf16* __restrict__ QKVb,
                                              bf16* __restrict__ VT, int N) {
  __shared__ float tr[64][33];
  __shared__ int rowcol[32];
  int t = threadIdx.x;
  int w = t >> 6, l = t & 63, fr = l & 15, fq = l >> 4;
  int rh = w & 1, ch = w >> 1;
  int m0 = blockIdx.x * 32, n0 = blockIdx.y * 64;
  if (t < 32) {
    int m = m0 + t; if (m > N - 1) m = N - 1;
    int b = batch[m];
    rowcol[t] = b * 512 + (m - offs[b]);
  }
  int arow = m0 + rh * 16 + fr; if (arow > N - 1) arow = N - 1;
  bf16x8 af[8];
  #pragma unroll
  for (int kt = 0; kt < 8; ++kt)
    af[kt] = ldcvt8(x + (size_t)arow * 256 + kt * 32 + fq * 8);
  #pragma unroll
  for (int p = 0; p < 3; ++p) {
    f32x4 acc[2];
    #pragma unroll
    for (int nt = 0; nt < 2; ++nt) {
      acc[nt] = (f32x4){0.f, 0.f, 0.f, 0.f};
      int brow = p * 256 + n0 + ch * 32 + nt * 16 + fr;
      #pragma unroll
      for (int kt = 0; kt < 8; ++kt) {
        bf16x8 bf_ = *(const bf16x8*)(Wqkv_t + (size_t)brow * 256 + kt * 32 + fq * 8);
        acc[nt] = __builtin_amdgcn_mfma_f32_16x16x32_bf16(af[kt], bf_, acc[nt], 0, 0, 0);
      }
    }
    float sc = (p == 0) ? QSCALE : 1.f;
    #pragma unroll
    for (int nt = 0; nt < 2; ++nt) {
      int col = p * 256 + n0 + ch * 32 + nt * 16 + fr;
      #pragma unroll
      for (int rr = 0; rr < 4; ++rr) {
        int m = m0 + rh * 16 + fq * 4 + rr;
        if (m < N) QKVb[(size_t)m * 768 + col] = __float2bfloat16(acc[nt][rr] * sc);
      }
    }
    if (p == 2) {  // V^T side output
      #pragma unroll
      for (int nt = 0; nt < 2; ++nt)
        #pragma unroll
        for (int rr = 0; rr < 4; ++rr)
          tr[ch * 32 + nt * 16 + fr][rh * 16 + fq * 4 + rr] = acc[nt][rr];
      __syncthreads();
      int c = t >> 2, rr0 = (t & 3) * 8;
      int dg = n0 + c;  // head*32 + d
      #pragma unroll
      for (int i = 0; i < 8; ++i) {
        int r = rr0 + i;
        VT[(size_t)dg * VT_LD + rowcol[r]] = __float2bfloat16(tr[c][r]);
      }
    }
  }
}

// ---------------- K3: fused MFMA flash attention, barrier-free main loop ----------------
// block = (q-tile 16, graph, j-chunk of JC). 4 waves, wave = heads {w, w+4}.
// Bias computed INLINE per lane (no producer/consumer LDS tiles, no loop barriers):
// lane (fr,fq), reg rr needs bias at (q = fq*4+rr, j in {fr, fr+16}) — 8 pairs.
// positions staged planar in LDS; bias table bf16 packed {h, h+4} per u32 so one
// ds_read_b32 serves both of the wave's heads.
__global__ __launch_bounds__(256) void k_attn(const float* __restrict__ pos,
                                              const float* __restrict__ Tblg,
                                              const bf16* __restrict__ QKVb,
                                              const bf16* __restrict__ VT,
                                              const int* __restrict__ offs,
                                              float* __restrict__ Op,
                                              float* __restrict__ lp, int N, int JC) {
  __shared__ unsigned int T2u[1536];            // [i][hp]: packed bf16 {h=hp, h=hp+4}
  __shared__ float px[512], py[512], pz[512];   // graph positions, planar
  __shared__ __align__(16) bf16 Pt[4][16][40];  // per-wave P C->A transform
  int b = blockIdx.y, jc = blockIdx.z;
  int off = offs[b], n = offs[b + 1] - off;
  int q0 = blockIdx.x * 16;
  if (q0 >= n) return;
  int t = threadIdx.x, w = t >> 6, l = t & 63, fr = l & 15, fq = l >> 4;

  // ---- stage bias table (pack head pairs) ----
  for (int e = t; e < 1536; e += 256) {
    int i = e >> 2, hp = e & 3;
    bf16 blo = __float2bfloat16(Tblg[i * 8 + hp]);
    bf16 bhi = __float2bfloat16(Tblg[i * 8 + hp + 4]);
    unsigned short ulo = *(unsigned short*)&blo, uhi = *(unsigned short*)&bhi;
    T2u[e] = (unsigned)ulo | ((unsigned)uhi << 16);
  }
  // ---- stage positions planar (coalesced read, scatter to planes) ----
  int n3 = n * 3;
  for (int idx = t; idx < n3; idx += 256) {
    float v = pos[(size_t)off * 3 + idx];
    int slot = idx / 3, c = idx - slot * 3;
    if (c == 0) px[slot] = v; else if (c == 1) py[slot] = v; else pz[slot] = v;
  }

  int h0 = w, h1 = w + 4;
  const bf16* Kb0 = QKVb + (size_t)off * 768 + 256 + h0 * 32 + fq * 8;
  const bf16* Kb1 = QKVb + (size_t)off * 768 + 256 + h1 * 32 + fq * 8;
  const bf16* Vb0 = VT + (size_t)(h0 * 32 + fr) * VT_LD + b * 512 + fq * 8;
  const bf16* Vb1 = VT + (size_t)(h1 * 32 + fr) * VT_LD + b * 512 + fq * 8;
  int qrow = q0 + fr; bool qv = qrow < n;
  size_t qoff = (size_t)(qv ? off + qrow : off) * 768 + fq * 8;
  bf16x8 aq[2];
  aq[0] = *(const bf16x8*)(QKVb + qoff + h0 * 32);
  aq[1] = *(const bf16x8*)(QKVb + qoff + h1 * 32);
  if (!qv) { aq[0] = (bf16x8){0,0,0,0,0,0,0,0}; aq[1] = aq[0]; }

  __syncthreads();  // staging done — no barriers after this point

  // q positions for this lane's 4 C-fragment rows
  float qx[4], qy[4], qz[4];
  #pragma unroll
  for (int rr = 0; rr < 4; ++rr) {
    int qq = q0 + fq * 4 + rr; if (qq >= n) qq = n - 1;
    qx[rr] = px[qq]; qy[rr] = py[qq]; qz[rr] = pz[qq];
  }

  f32x4 Oa[2][2];
  Oa[0][0] = (f32x4){0.f,0.f,0.f,0.f}; Oa[0][1] = Oa[0][0];
  Oa[1][0] = Oa[0][0];                 Oa[1][1] = Oa[0][0];
  float lacc[2][4] = {{0.f,0.f,0.f,0.f},{0.f,0.f,0.f,0.f}};
  int jtiles = (n + 31) >> 5;
  int jt0 = (jtiles * jc) / JC, jt1 = (jtiles * (jc + 1)) / JC;

  for (int jt = jt0; jt < jt1; ++jt) {
    // ---- K/V tile loads: issue first, latency hidden under bias math ----
    int k0 = jt * 32 + fr, k1 = k0 + 16;
    size_t r0 = (size_t)((k0 < n) ? k0 : 0) * 768;
    size_t r1 = (size_t)((k1 < n) ? k1 : 0) * 768;
    bf16x8 ck00 = *(const bf16x8*)(Kb0 + r0), ck01 = *(const bf16x8*)(Kb0 + r1);
    bf16x8 ck10 = *(const bf16x8*)(Kb1 + r0), ck11 = *(const bf16x8*)(Kb1 + r1);
    bf16x8 cv00 = *(const bf16x8*)(Vb0 + jt * 32);
    bf16x8 cv01 = *(const bf16x8*)(Vb0 + (size_t)16 * VT_LD + jt * 32);
    bf16x8 cv10 = *(const bf16x8*)(Vb1 + jt * 32);
    bf16x8 cv11 = *(const bf16x8*)(Vb1 + (size_t)16 * VT_LD + jt * 32);

    // ---- inline bias: 8 (q,j) pairs per lane ----
    bool vj0 = k0 < n, vj1 = k1 < n;
    int js0 = vj0 ? k0 : 0, js1 = vj1 ? k1 : 0;
    float jx0 = px[js0], jy0 = py[js0], jz0 = pz[js0];
    float jx1 = px[js1], jy1 = py[js1], jz1 = pz[js1];
    float bias[2][2][4];  // [jti][hh][rr]
    #pragma unroll
    for (int rr = 0; rr < 4; ++rr) {
      {
        float dx = qx[rr] - jx0, dy = qy[rr] - jy0, dz = qz[rr] - jz0;
        float fi = sqrtf(dx * dx + dy * dy + dz * dz) * 8.0f;
        int i = (int)fi; if (i > 382) i = 382;
        float f2 = fi - (float)i;
        unsigned ua = T2u[i * 4 + w], ub = T2u[i * 4 + 4 + w];
        float la = __uint_as_float(ua << 16), ha = __uint_as_float(ua & 0xffff0000u);
        float lb = __uint_as_float(ub << 16), hb = __uint_as_float(ub & 0xffff0000u);
        bias[0][0][rr] = vj0 ? (la + f2 * (lb - la)) : -1e30f;
        bias[0][1][rr] = vj0 ? (ha + f2 * (hb - ha)) : -1e30f;
      }
      {
        float dx = qx[rr] - jx1, dy = qy[rr] - jy1, dz = qz[rr] - jz1;
        float fi = sqrtf(dx * dx + dy * dy + dz * dz) * 8.0f;
        int i = (int)fi; if (i > 382) i = 382;
        float f2 = fi - (float)i;
        unsigned ua = T2u[i * 4 + w], ub = T2u[i * 4 + 4 + w];
        float la = __uint_as_float(ua << 16), ha = __uint_as_float(ua & 0xffff0000u);
        float lb = __uint_as_float(ub << 16), hb = __uint_as_float(ub & 0xffff0000u);
        bias[1][0][rr] = vj1 ? (la + f2 * (lb - la)) : -1e30f;
        bias[1][1][rr] = vj1 ? (ha + f2 * (hb - ha)) : -1e30f;
      }
    }

    // ---- QK^T -> +bias -> exp -> P -> PV, per head ----
    #pragma unroll
    for (int hh = 0; hh < 2; ++hh) {
      f32x4 z = {0.f, 0.f, 0.f, 0.f};
      f32x4 S0 = __builtin_amdgcn_mfma_f32_16x16x32_bf16(aq[hh], hh ? ck10 : ck00, z, 0, 0, 0);
      f32x4 S1 = __builtin_amdgcn_mfma_f32_16x16x32_bf16(aq[hh], hh ? ck11 : ck01, z, 0, 0, 0);
      #pragma unroll
      for (int k = 0; k < 8; ++k) {
        int jti = k >> 2, rr = k & 3;
        float s = (jti ? S1[rr] : S0[rr]) + bias[jti][hh][rr];
        float p = __expf(s);
        lacc[hh][rr] += p;
        Pt[w][fq * 4 + rr][jti * 16 + fr] = __float2bfloat16(p);
      }
      bf16x8 ap = *(const bf16x8*)&Pt[w][fr][fq * 8];
      Oa[hh][0] = __builtin_amdgcn_mfma_f32_16x16x32_bf16(ap, hh ? cv10 : cv00, Oa[hh][0], 0, 0, 0);
      Oa[hh][1] = __builtin_amdgcn_mfma_f32_16x16x32_bf16(ap, hh ? cv11 : cv01, Oa[hh][1], 0, 0, 0);
    }
  }

  #pragma unroll
  for (int hh = 0; hh < 2; ++hh)
    #pragma unroll
    for (int rr = 0; rr < 4; ++rr) {
      #pragma unroll
      for (int m2 = 1; m2 <= 8; m2 <<= 1) lacc[hh][rr] += __shfl_xor(lacc[hh][rr], m2);
    }
  float* Opc = Op + (size_t)jc * N * 256;
  float* lpc = lp + (size_t)jc * N * 8;
  #pragma unroll
  for (int hh = 0; hh < 2; ++hh) {
    int h = w + 4 * hh;
    #pragma unroll
    for (int rr = 0; rr < 4; ++rr) {
      int row = q0 + fq * 4 + rr;
      if (row < n) {
        #pragma unroll
        for (int dh = 0; dh < 2; ++dh)
          Opc[(size_t)(off + row) * 256 + h * 32 + dh * 16 + fr] = Oa[hh][dh][rr];
        if (fr == 0) lpc[(size_t)(off + row) * 8 + h] = lacc[hh][rr];
      }
    }
  }
}

// ---------------- K4: combine JC j-partials + out-proj GEMM + residual + LN ----------------
__global__ __launch_bounds__(256) void k_out_ln(const float* __restrict__ Op,
                                                const float* __restrict__ lp,
                                                const bf16* __restrict__ Bt,
                                                const float* __restrict__ x,
                                                const float* __restrict__ gamma,
                                                const float* __restrict__ beta,
                                                float* __restrict__ out, int M, int JC) {
  __shared__ float ps[4][16], pss[4][16];
  int t = threadIdx.x, w = t >> 6, l = t & 63, fr = l & 15, fq = l >> 4;
  int m0 = blockIdx.x * 16;
  int arow = m0 + fr; if (arow > M - 1) arow = M - 1;
  float linv[8];
  {
    float ls[8] = {0.f,0.f,0.f,0.f,0.f,0.f,0.f,0.f};
    for (int c = 0; c < JC; ++c) {
      const float* p = lp + ((size_t)c * M + arow) * 8;
      float4 a0 = *(const float4*)p, a1 = *(const float4*)(p + 4);
      ls[0] += a0.x; ls[1] += a0.y; ls[2] += a0.z; ls[3] += a0.w;
      ls[4] += a1.x; ls[5] += a1.y; ls[6] += a1.z; ls[7] += a1.w;
    }
    #pragma unroll
    for (int h = 0; h < 8; ++h) linv[h] = 1.f / ls[h];
  }
  bf16x8 af[8];
  #pragma unroll
  for (int kt = 0; kt < 8; ++kt) {  // head h == kt (32 d per head)
    size_t o = (size_t)arow * 256 + kt * 32 + fq * 8;
    float s0 = 0.f, s1 = 0.f, s2 = 0.f, s3 = 0.f, s4 = 0.f, s5 = 0.f, s6 = 0.f, s7 = 0.f;
    for (int c = 0; c < JC; ++c) {
      const float* p = Op + (size_t)c * M * 256 + o;
      float4 u = *(const float4*)p, v = *(const float4*)(p + 4);
      s0 += u.x; s1 += u.y; s2 += u.z; s3 += u.w;
      s4 += v.x; s5 += v.y; s6 += v.z; s7 += v.w;
    }
    float li = linv[kt];
    __align__(16) bf16 tmp[8];
    tmp[0] = __float2bfloat16(s0 * li); tmp[1] = __float2bfloat16(s1 * li);
    tmp[2] = __float2bfloat16(s2 * li); tmp[3] = __float2bfloat16(s3 * li);
    tmp[4] = __float2bfloat16(s4 * li); tmp[5] = __float2bfloat16(s5 * li);
    tmp[6] = __float2bfloat16(s6 * li); tmp[7] = __float2bfloat16(s7 * li);
    af[kt] = *(const bf16x8*)tmp;
  }
  f32x4 acc[4];
  #pragma unroll
  for (int nt = 0; nt < 4; ++nt) {
    acc[nt] = (f32x4){0.f, 0.f, 0.f, 0.f};
    int brow = w * 64 + nt * 16 + fr;
    #pragma unroll
    for (int kt = 0; kt < 8; ++kt) {
      bf16x8 bf_ = *(const bf16x8*)(Bt + (size_t)brow * 256 + kt * 32 + fq * 8);
      acc[nt] = __builtin_amdgcn_mfma_f32_16x16x32_bf16(af[kt], bf_, acc[nt], 0, 0, 0);
    }
  }
  float y[4][4];
  #pragma unroll
  for (int rr = 0; rr < 4; ++rr) {
    int row = m0 + fq * 4 + rr;
    int rc = (row < M) ? row : (M - 1);
    float s = 0.f, ss = 0.f;
    #pragma unroll
    for (int nt = 0; nt < 4; ++nt) {
      float v = acc[nt][rr] + x[(size_t)rc * 256 + w * 64 + nt * 16 + fr];
      y[rr][nt] = v; s += v; ss += v * v;
    }
    #pragma unroll
    for (int m2 = 1; m2 <= 8; m2 <<= 1) { s += __shfl_xor(s, m2); ss += __shfl_xor(ss, m2); }
    if (fr == 0) { ps[w][fq * 4 + rr] = s; pss[w][fq * 4 + rr] = ss; }
  }
  __syncthreads();
  #pragma unroll
  for (int rr = 0; rr < 4; ++rr) {
    int row = m0 + fq * 4 + rr;
    int ri = fq * 4 + rr;
    float s = ps[0][ri] + ps[1][ri] + ps[2][ri] + ps[3][ri];
    float ss = pss[0][ri] + pss[1][ri] + pss[2][ri] + pss[3][ri];
    float mean = s * (1.f / 256.f);
    float var = ss * (1.f / 256.f) - mean * mean;
    float rstd = rsqrtf(var + 1e-5f);
    if (row < M) {
      #pragma unroll
      for (int nt = 0; nt < 4; ++nt) {
        int col = w * 64 + nt * 16 + fr;
        out[(size_t)row * 256 + col] = gamma[col] * (y[rr][nt] - mean) * rstd + beta[col];
      }
    }
  }
}

extern "C" void kernel_launch(void* const* d_in, const int* in_sizes, int n_in,
                              void* d_out, int out_size, void* d_ws, size_t ws_size,
                              hipStream_t stream) {
  (void)n_in; (void)out_size;
  const float* x     = (const float*)d_in[0];
  const float* pos   = (const float*)d_in[1];
  const int*   batch = (const int*)d_in[2];
  const float* Wqkv  = (const float*)d_in[3];
  const float* Wout  = (const float*)d_in[4];
  const float* freqs = (const float*)d_in[5];
  const float* Wrope = (const float*)d_in[6];
  const float* gamma = (const float*)d_in[7];
  const float* beta  = (const float*)d_in[8];
  float* out = (float*)d_out;

  int N = in_sizes[0] / 256;  // 6137

  // 4-way j-split needs ~40.1 MB of workspace; fall back to 2-way if tight
  int JC = (ws_size >= (size_t)41 * 1024 * 1024) ? 4 : 2;

  char* base = (char*)d_ws;
  int*   offs   = (int*)base;                   // @0 (1 KB)
  bf16*  QKVb   = (bf16*)(base + 1024);         // N*768*2  = 9,426,432
  bf16*  VT     = (bf16*)(base + 9427456);      // 4,194,304
  bf16*  Wqkv_t = (bf16*)(base + 13621760);     // 393,216
  bf16*  Wout_t = (bf16*)(base + 14014976);     // 131,072
  float* Tblg   = (float*)(base + 14146048);    // 12,288
  float* Op     = (float*)(base + 14158336);    // JC x N*256*4
  float* lp     = (float*)(base + 14158336 + (size_t)JC * N * 1024);  // JC x N*8*4

  int MBm = (N + 31) / 32;  // 192
  k_pre<<<67, 256, 0, stream>>>(Wqkv, Wout, batch, freqs, Wrope, Wqkv_t, Wout_t, Tblg, offs, N);
  k_gemm<<<dim3(MBm, 4), 256, 0, stream>>>(x, Wqkv_t, batch, offs, QKVb, VT, N);
  k_attn<<<dim3(32, NGRAPH, JC), 256, 0, stream>>>(pos, Tblg, QKVb, VT, offs, Op, lp, N, JC);
  k_out_ln<<<(N + 15) / 16, 256, 0, stream>>>(Op, lp, Wout_t, x, gamma, beta, out, N, JC);
}